// Round 8
// baseline (584.543 us; speedup 1.0000x reference)
//
#include <hip/hip_runtime.h>
#include <math.h>
#include <stdint.h>

#define D 128
#define MAXNORM (1.0f - 4e-3f)
#define ART_CLAMP 0.9999999f  /* fp32(1 - 1e-7) */
#define BKT_BITS 7             /* 128 nodes per bucket */
#define BKT_NODES 128
#define BKT_CAP 4096           /* LDS sort capacity; mean deg*128 = 2048, 40 sigma margin */
#define LSTR 132               /* k-major LDS row stride (x4B: 528 = 16B-aligned, odd/32 banks) */

// butterfly all-reduce: every lane ends with the 64-lane total
__device__ __forceinline__ float waveAllReduce(float v) {
#pragma unroll
    for (int off = 32; off; off >>= 1) v += __shfl_xor(v, off, 64);
    return v;
}

// all-reduce across a 16-lane group (lanes differing in low 4 bits)
__device__ __forceinline__ float reduce16(float v) {
    v += __shfl_xor(v, 8, 64);
    v += __shfl_xor(v, 4, 64);
    v += __shfl_xor(v, 2, 64);
    v += __shfl_xor(v, 1, 64);
    return v;
}

// fp32 -> bf16 bits, round-to-nearest-even
__device__ __forceinline__ uint16_t f2bf(float f) {
    uint32_t u = __float_as_uint(f);
    uint32_t r = u + 0x7FFFu + ((u >> 16) & 1u);
    return (uint16_t)(r >> 16);
}

// ---------------- hyperbolic bias: hb = proj(expmap0(b)), one wave -----------

__global__ __launch_bounds__(64) void biasKernel(const float* __restrict__ B1,
                                                 const float* __restrict__ B2,
                                                 float* __restrict__ HBOUT) {
    int lane = threadIdx.x;
    const float* B = blockIdx.x ? B2 : B1;
    float v0 = B[lane], v1 = B[lane + 64];
    float nn = fmaxf(sqrtf(waveAllReduce(v0 * v0 + v1 * v1)), 1e-15f);
    float t = tanhf(nn);
    float sc = t / nn;
    float pn = fmaxf(t, 1e-15f);
    if (pn > MAXNORM) sc *= MAXNORM / pn;
    HBOUT[blockIdx.x * D + lane] = v0 * sc;
    HBOUT[blockIdx.x * D + lane + 64] = v1 * sc;
}

// ---------------- W transpose: Wt[k][j] = W[j][k] ----------------------------

__global__ __launch_bounds__(256) void transposeW(const float* __restrict__ W1,
                                                  const float* __restrict__ W2,
                                                  float* __restrict__ Wt1,
                                                  float* __restrict__ Wt2) {
    int idx = blockIdx.x * 256 + threadIdx.x;  // 0..16383
    int k = idx >> 7, j = idx & 127;
    Wt1[idx] = W1[j * 128 + k];
    Wt2[idx] = W2[j * 128 + k];
}

// ---------------- raw row norms of X (for layer-1 encoder fold) --------------

__global__ __launch_bounds__(256) void rowNorms(const float* __restrict__ X,
                                                float* __restrict__ XN, int n) {
    int lane = threadIdx.x & 63;
    int wv = (blockIdx.x * 256 + threadIdx.x) >> 6;
    int nw = (gridDim.x * 256) >> 6;
    for (int r = wv; r < n; r += nw) {
        float2 v = *(const float2*)(X + (size_t)r * D + lane * 2);
        float nn = sqrtf(waveAllReduce(v.x * v.x + v.y * v.y));
        if (lane == 0) XN[r] = nn;
    }
}

// ---------------- bucket binning ---------------------------------------------

__global__ __launch_bounds__(256) void bucketHisto(const int* __restrict__ DST,
                                                   int* __restrict__ bcnt, int E, int B) {
    __shared__ int cnt[1024];
    int tid = threadIdx.x;
    for (int i = tid; i < B; i += 256) cnt[i] = 0;
    __syncthreads();
    int start = blockIdx.x * 8192;
    int endE = min(start + 8192, E);
    for (int e = start + tid; e < endE; e += 256)
        atomicAdd(&cnt[DST[e] >> BKT_BITS], 1);
    __syncthreads();
    for (int i = tid; i < B; i += 256)
        if (cnt[i]) atomicAdd(&bcnt[i], cnt[i]);
}

// single block: exclusive scan of bcnt (B <= 1024) -> boff, gcur; rp[n]=boff[B]=E
__global__ __launch_bounds__(1024) void bucketScan(const int* __restrict__ bcnt,
                                                   int* __restrict__ boff,
                                                   int* __restrict__ gcur,
                                                   int* __restrict__ rp_last,
                                                   int B, int E) {
    __shared__ int sd[1024];
    int tid = threadIdx.x;
    int v = (tid < B) ? bcnt[tid] : 0;
    sd[tid] = v;
    __syncthreads();
    for (int off = 1; off < 1024; off <<= 1) {
        int t = (tid >= off) ? sd[tid - off] : 0;
        __syncthreads();
        sd[tid] += t;
        __syncthreads();
    }
    int ex = sd[tid] - v;
    if (tid < B) { boff[tid] = ex; gcur[tid] = ex; }
    if (tid == 0) { boff[B] = E; *rp_last = E; }
}

__global__ __launch_bounds__(256) void binEdges(const int* __restrict__ DST,
                                                const int* __restrict__ SRC,
                                                const float* __restrict__ EW,
                                                int* __restrict__ gcur,
                                                int2* __restrict__ binned, int E, int B) {
    __shared__ int cnt[1024];
    __shared__ int base[1024];
    int tid = threadIdx.x;
    int start = blockIdx.x * 8192;
    int endE = min(start + 8192, E);
    for (int i = tid; i < B; i += 256) cnt[i] = 0;
    __syncthreads();
    for (int e = start + tid; e < endE; e += 256)
        atomicAdd(&cnt[DST[e] >> BKT_BITS], 1);
    __syncthreads();
    for (int i = tid; i < B; i += 256) {
        int c = cnt[i];
        base[i] = (c > 0) ? atomicAdd(&gcur[i], c) : 0;
        cnt[i] = 0;
    }
    __syncthreads();
    for (int e = start + tid; e < endE; e += 256) {
        int d = DST[e];
        int bk = d >> BKT_BITS;
        int r = atomicAdd(&cnt[bk], 1);
        binned[base[bk] + r] =
            make_int2(SRC[e] | ((d & (BKT_NODES - 1)) << 24), __float_as_int(EW[e]));
    }
}

// ---------------- per-bucket counting sort -> exact CSR ----------------------

__global__ __launch_bounds__(256) void perBucketSort(int2* __restrict__ binned,
                                                     const int* __restrict__ boff,
                                                     int* __restrict__ rp, int n) {
    __shared__ int cnt[BKT_NODES];
    __shared__ int cur[BKT_NODES];
    __shared__ int2 buf[BKT_CAP];
    int tid = threadIdx.x;
    int b = blockIdx.x;
    int beg = boff[b], end = boff[b + 1];

    if (tid < BKT_NODES) cnt[tid] = 0;
    __syncthreads();
    for (int e = beg + tid; e < end; e += 256)
        atomicAdd(&cnt[((uint32_t)binned[e].x) >> 24], 1);
    __syncthreads();
    // exclusive scan over 128 counters (Hillis-Steele, uniform syncs)
    int v = (tid < BKT_NODES) ? cnt[tid] : 0;
    if (tid < BKT_NODES) cur[tid] = v;
    __syncthreads();
    for (int off = 1; off < BKT_NODES; off <<= 1) {
        int t = (tid < BKT_NODES && tid >= off) ? cur[tid - off] : 0;
        __syncthreads();
        if (tid < BKT_NODES) cur[tid] += t;
        __syncthreads();
    }
    if (tid < BKT_NODES) {
        int ex = cur[tid] - v;
        int g = b * BKT_NODES + tid;
        if (g < n) rp[g] = beg + ex;
        cur[tid] = ex;   // scatter cursor
    }
    __syncthreads();
    for (int e = beg + tid; e < end; e += 256) {
        int2 pr = binned[e];
        int dl = ((uint32_t)pr.x) >> 24;
        int pos = atomicAdd(&cur[dl], 1);
        if (pos < BKT_CAP) buf[pos] = make_int2(pr.x & 0x00FFFFFF, pr.y);
    }
    __syncthreads();
    int cnt_tot = end - beg;
    for (int i = tid; i < cnt_tot && i < BKT_CAP; i += 256)
        binned[beg + i] = buf[i];
}

// ---------------- fused GEMM + HypLinear epilogue ----------------------------
// k-major LDS layout + 2x2-quadrant register tile: inner loop = 4 ds_read_b128
// per k-step (was 16 ds_read_b32) -> LDS pipe demand ~48 cyc/k vs ~93.
// Thread owns rows {4ty+0..3, 64+4ty+0..3}, cols {4tx+0..3, 64+4tx+0..3}.

template <bool ENCODE>
__global__ __launch_bounds__(256) void gemmA(const float* __restrict__ A,
                                             const float* __restrict__ Wt,
                                             const float* __restrict__ XN,
                                             const float* __restrict__ HB,
                                             uint16_t* __restrict__ XT, int n) {
    __shared__ float As[32 * LSTR];   // As[k][r]
    __shared__ float Ws[32 * LSTR];   // Ws[k][j]
    int tid = threadIdx.x;
    int tx = tid & 15, ty = tid >> 4;
    int rowBase = blockIdx.x * 128;

    // column map: j(c) = 4*tx + (c&3) + (c>>2)*64
    float hbf[8];
#pragma unroll
    for (int c = 0; c < 8; c++) hbf[c] = HB[4 * tx + (c & 3) + (c >> 2) * 64];
    float hbsq = 0.f;
#pragma unroll
    for (int c = 0; c < 8; c++) hbsq += hbf[c] * hbf[c];
    float hb2 = reduce16(hbsq);

    float acc[8][8] = {};
    for (int q = 0; q < 4; q++) {
        if (q) __syncthreads();
        // stage A quarter TRANSPOSED: As[k][r] <- A[rowBase+r][q*32+k]
#pragma unroll
        for (int c = 0; c < 4; c++) {
            int f = c * 256 + tid;
            int r = f >> 3, k4 = (f & 7) << 2;
            int gr = rowBase + r;
            if (gr >= n) gr = n - 1;  // clamp; epilogue guarded
            float4 v = *(const float4*)(A + (size_t)gr * D + q * 32 + k4);
            As[(k4 + 0) * LSTR + r] = v.x;
            As[(k4 + 1) * LSTR + r] = v.y;
            As[(k4 + 2) * LSTR + r] = v.z;
            As[(k4 + 3) * LSTR + r] = v.w;
        }
        // stage Wt quarter: Ws[k][j] <- Wt[q*32+k][j]  (coalesced b128)
#pragma unroll
        for (int c = 0; c < 4; c++) {
            int f = c * 256 + tid;
            int k = f >> 5, j4 = (f & 31) << 2;
            float4 v = *(const float4*)(Wt + (size_t)(q * 32 + k) * D + j4);
            *(float4*)(Ws + k * LSTR + j4) = v;
        }
        __syncthreads();
#pragma unroll 4
        for (int k = 0; k < 32; k++) {
            const float4 a0 = *(const float4*)(As + k * LSTR + 4 * ty);
            const float4 a1 = *(const float4*)(As + k * LSTR + 64 + 4 * ty);
            const float4 w0 = *(const float4*)(Ws + k * LSTR + 4 * tx);
            const float4 w1 = *(const float4*)(Ws + k * LSTR + 64 + 4 * tx);
            float a[8] = {a0.x, a0.y, a0.z, a0.w, a1.x, a1.y, a1.z, a1.w};
            float w[8] = {w0.x, w0.y, w0.z, w0.w, w1.x, w1.y, w1.z, w1.w};
#pragma unroll
            for (int rr = 0; rr < 8; rr++)
#pragma unroll
                for (int cc = 0; cc < 8; cc++) acc[rr][cc] += a[rr] * w[cc];
        }
    }

    // ---- fused epilogue (rows 4ty+(rr&3)+(rr>>2)*64; uniform across tx-group)
#pragma unroll
    for (int rr = 0; rr < 8; rr++) {
        int row = rowBase + 4 * ty + (rr & 3) + (rr >> 2) * 64;
        if (row >= n) continue;
        float s = 0.f;
#pragma unroll
        for (int c = 0; c < 8; c++) s += acc[rr][c] * acc[rr][c];
        float yn2 = reduce16(s);
        float sc, xns;
        if (ENCODE) {
            float nn = fmaxf(XN[row], 1e-15f);
            float t = tanhf(nn);
            sc = t / nn;                        // expmap0 scale
            float pn = fmaxf(t, 1e-15f);
            if (pn > MAXNORM) { sc *= MAXNORM / pn; pn = MAXNORM; }  // proj
            xns = pn;
        } else {
            sc = 1.0f;
            xns = fmaxf(XN[row], 1e-15f);
        }
        float mxn2 = sc * sc * yn2;
        float mxn = fmaxf(sqrtf(mxn2), 1e-15f);
        float arg = (mxn / xns) * atanhf(fminf(xns, ART_CLAMP));
        float t = tanhf(arg);
        float s2 = (mxn2 == 0.0f) ? 0.0f : (sc * t / mxn);  // zero-row guard
        float h[8];
#pragma unroll
        for (int c = 0; c < 8; c++) h[c] = acc[rr][c] * s2;
        float rn = fmaxf(t, 1e-15f);   // ||res|| == t analytically
        float hn = rn;
        if (rn > MAXNORM) {
            float f = MAXNORM / rn;
#pragma unroll
            for (int c = 0; c < 8; c++) h[c] *= f;
            hn = MAXNORM;
        }
        float x2 = hn * hn;
        float d0 = 0.f;
#pragma unroll
        for (int c = 0; c < 8; c++) d0 += h[c] * hbf[c];
        float xy = reduce16(d0);
        float k1 = 1.0f + 2.0f * xy + hb2;
        float k2 = 1.0f - x2;
        float den = fmaxf(1.0f + 2.0f * xy + x2 * hb2, 1e-15f);
        float av[8];
        float s3 = 0.f;
#pragma unroll
        for (int c = 0; c < 8; c++) {
            av[c] = (k1 * h[c] + k2 * hbf[c]) / den;
            s3 += av[c] * av[c];
        }
        float an = fmaxf(sqrtf(reduce16(s3)), 1e-15f);
        float fproj = 1.0f;
        if (an > MAXNORM) { fproj = MAXNORM / an; an = MAXNORM; }
        float lm = fproj * atanhf(fminf(an, ART_CLAMP)) / an;  // proj+logmap0
        uint16_t* o = XT + (size_t)row * D;
        uint2 p0, p1;
        p0.x = (uint32_t)f2bf(av[0] * lm) | ((uint32_t)f2bf(av[1] * lm) << 16);
        p0.y = (uint32_t)f2bf(av[2] * lm) | ((uint32_t)f2bf(av[3] * lm) << 16);
        p1.x = (uint32_t)f2bf(av[4] * lm) | ((uint32_t)f2bf(av[5] * lm) << 16);
        p1.y = (uint32_t)f2bf(av[6] * lm) | ((uint32_t)f2bf(av[7] * lm) << 16);
        *(uint2*)(o + 4 * tx) = p0;
        *(uint2*)(o + 64 + 4 * tx) = p1;
    }
}

// ---------------- CSR aggregation + HypAct -----------------------------------
// Wave per node (max MLP for the random gather): bf16 rows, fp32 accumulate,
// stage-C epilogue inline. STORE_HN: store analytic output norm.

template <bool STORE_HN>
__global__ __launch_bounds__(256) void aggC(const uint16_t* __restrict__ XT,
                                            const int* __restrict__ rp,
                                            const int2* __restrict__ sorted,
                                            float* __restrict__ OUT,
                                            float* __restrict__ HN, int n) {
    int g = (blockIdx.x * 256 + threadIdx.x) >> 6;
    int lane = threadIdx.x & 63;
    if (g >= n) return;
    int beg = rp[g], end = rp[g + 1];
    float a0 = 0.f, a1 = 0.f;
    int j = beg;
    for (; j + 3 < end; j += 4) {
        int2 s0 = sorted[j], s1 = sorted[j + 1], s2 = sorted[j + 2], s3 = sorted[j + 3];
        uint32_t u0 = ((const uint32_t*)(XT + (size_t)s0.x * D))[lane];
        uint32_t u1 = ((const uint32_t*)(XT + (size_t)s1.x * D))[lane];
        uint32_t u2 = ((const uint32_t*)(XT + (size_t)s2.x * D))[lane];
        uint32_t u3 = ((const uint32_t*)(XT + (size_t)s3.x * D))[lane];
        float w0 = __int_as_float(s0.y), w1 = __int_as_float(s1.y);
        float w2 = __int_as_float(s2.y), w3 = __int_as_float(s3.y);
        a0 += __uint_as_float(u0 << 16) * w0 + __uint_as_float(u1 << 16) * w1 +
              __uint_as_float(u2 << 16) * w2 + __uint_as_float(u3 << 16) * w3;
        a1 += __uint_as_float(u0 & 0xFFFF0000u) * w0 + __uint_as_float(u1 & 0xFFFF0000u) * w1 +
              __uint_as_float(u2 & 0xFFFF0000u) * w2 + __uint_as_float(u3 & 0xFFFF0000u) * w3;
    }
    for (; j < end; j++) {
        int2 s0 = sorted[j];
        uint32_t u0 = ((const uint32_t*)(XT + (size_t)s0.x * D))[lane];
        float w0 = __int_as_float(s0.y);
        a0 += __uint_as_float(u0 << 16) * w0;
        a1 += __uint_as_float(u0 & 0xFFFF0000u) * w0;
    }
    // ---- stage C inline ----
    float nn = fmaxf(sqrtf(waveAllReduce(a0 * a0 + a1 * a1)), 1e-15f);
    float t = tanhf(nn);
    float sc = t / nn;                       // expmap0
    float pn = fmaxf(t, 1e-15f);
    if (pn > MAXNORM) { sc *= MAXNORM / pn; pn = MAXNORM; }  // proj
    float lm = atanhf(fminf(pn, ART_CLAMP)) / pn;            // logmap0
    float r0 = fmaxf(lm * sc * a0, 0.f);     // relu in tangent space
    float r1 = fmaxf(lm * sc * a1, 0.f);
    float rn = fmaxf(sqrtf(waveAllReduce(r0 * r0 + r1 * r1)), 1e-15f);
    float t2 = tanhf(rn);
    float sc2 = t2 / rn;                     // expmap0 at c_out
    float on = fmaxf(t2, 1e-15f);
    if (on > MAXNORM) { sc2 *= MAXNORM / on; on = MAXNORM; }
    *(float2*)(OUT + (size_t)g * D + lane * 2) = make_float2(r0 * sc2, r1 * sc2);
    if (STORE_HN && lane == 0) HN[g] = on;   // next layer's _norm(x)
}

// ---------------- launcher ---------------------------------------------------

extern "C" void kernel_launch(void* const* d_in, const int* in_sizes, int n_in,
                              void* d_out, int out_size, void* d_ws, size_t ws_size,
                              hipStream_t stream) {
    const float* x  = (const float*)d_in[0];
    const int*   ei = (const int*)d_in[1];
    const float* ew = (const float*)d_in[2];
    const float* w1 = (const float*)d_in[3];
    const float* b1 = (const float*)d_in[4];
    const float* w2 = (const float*)d_in[5];
    const float* b2 = (const float*)d_in[6];
    int n = in_sizes[0] / D;
    int E = in_sizes[2];
    int B = (n + BKT_NODES - 1) >> BKT_BITS;    // 782 for n=100000 (<= 1024)

    // workspace layout (~40 MB)
    uint16_t* xtb = (uint16_t*)d_ws;               // n*D bf16
    int*   bcnt = (int*)(xtb + (size_t)n * D);     // 1024
    int*   boff = bcnt + 1024;                     // 1025
    int*   gcur = boff + 1025;                     // 1024
    int*   rp   = gcur + 1024;                     // n+1
    float* xn   = (float*)(rp + n + 1);            // n (X norms, then H norms)
    float* wt1  = xn + n;                          // 128*128
    float* wt2  = wt1 + 128 * 128;                 // 128*128
    float* hb   = wt2 + 128 * 128;                 // 2*D
    uintptr_t p = (uintptr_t)(hb + 2 * D);
    int2* binned = (int2*)((p + 15) & ~(uintptr_t)15);  // E pairs (binned, then CSR-sorted)
    float* Hd = (float*)d_out;                     // H1 scratch + final out

    const int* dst = ei;      // edge_index[0] = segment ids (destinations)
    const int* src = ei + E;  // edge_index[1] = gather sources

    const int gE8 = (E + 8191) / 8192;
    const int gG = (n + 127) / 128;    // gemm tiles
    const int gAgg = (n + 3) / 4;      // wave per node

    biasKernel<<<2, 64, 0, stream>>>(b1, b2, hb);
    transposeW<<<64, 256, 0, stream>>>(w1, w2, wt1, wt2);
    rowNorms<<<1024, 256, 0, stream>>>(x, xn, n);

    // ---- CSR build: bucket-bin then per-bucket LDS counting sort ----
    hipMemsetAsync(bcnt, 0, 1024 * sizeof(int), stream);
    bucketHisto<<<gE8, 256, 0, stream>>>(dst, bcnt, E, B);
    bucketScan<<<1, 1024, 0, stream>>>(bcnt, boff, gcur, rp + n, B, E);
    binEdges<<<gE8, 256, 0, stream>>>(dst, src, ew, gcur, binned, E, B);
    perBucketSort<<<B, 256, 0, stream>>>(binned, boff, rp, n);

    // ---- layer 1 (encoder folded into gemmA epilogue) ----
    gemmA<true><<<gG, 256, 0, stream>>>(x, wt1, xn, hb, xtb, n);        // -> bf16 T1
    aggC<true><<<gAgg, 256, 0, stream>>>(xtb, rp, binned, Hd, xn, n);   // -> H1 + hn

    // ---- layer 2 ----
    gemmA<false><<<gG, 256, 0, stream>>>(Hd, wt2, xn, hb + D, xtb, n);  // -> bf16 T2
    aggC<false><<<gAgg, 256, 0, stream>>>(xtb, rp, binned, (float*)d_out, nullptr, n);
}

// Round 9
// 545.214 us; speedup vs baseline: 1.0721x; 1.0721x over previous
//
#include <hip/hip_runtime.h>
#include <math.h>
#include <stdint.h>

#define D 128
#define MAXNORM (1.0f - 4e-3f)
#define ART_CLAMP 0.9999999f  /* fp32(1 - 1e-7) */
#define BKT_BITS 7             /* 128 nodes per bucket */
#define BKT_NODES 128
#define BKT_CAP 4096           /* LDS sort capacity; mean deg*128 = 2048, 40 sigma margin */

typedef __attribute__((ext_vector_type(8))) short short8;   // 8 bf16 (4 VGPR)
typedef __attribute__((ext_vector_type(4))) float float4v;  // MFMA C/D (4 fp32)

// butterfly all-reduce: every lane ends with the 64-lane total
__device__ __forceinline__ float waveAllReduce(float v) {
#pragma unroll
    for (int off = 32; off; off >>= 1) v += __shfl_xor(v, off, 64);
    return v;
}

// all-reduce across a 16-lane group (lanes differing in low 4 bits)
__device__ __forceinline__ float reduce16(float v) {
    v += __shfl_xor(v, 8, 64);
    v += __shfl_xor(v, 4, 64);
    v += __shfl_xor(v, 2, 64);
    v += __shfl_xor(v, 1, 64);
    return v;
}

// fp32 -> bf16 bits, round-to-nearest-even
__device__ __forceinline__ uint16_t f2bf(float f) {
    uint32_t u = __float_as_uint(f);
    uint32_t r = u + 0x7FFFu + ((u >> 16) & 1u);
    return (uint16_t)(r >> 16);
}
__device__ __forceinline__ float bf2f(uint16_t b) {
    return __uint_as_float((uint32_t)b << 16);
}

// ---------------- hyperbolic bias: hb = proj(expmap0(b)), one wave -----------

__global__ __launch_bounds__(64) void biasKernel(const float* __restrict__ B1,
                                                 const float* __restrict__ B2,
                                                 float* __restrict__ HBOUT) {
    int lane = threadIdx.x;
    const float* B = blockIdx.x ? B2 : B1;
    float v0 = B[lane], v1 = B[lane + 64];
    float nn = fmaxf(sqrtf(waveAllReduce(v0 * v0 + v1 * v1)), 1e-15f);
    float t = tanhf(nn);
    float sc = t / nn;
    float pn = fmaxf(t, 1e-15f);
    if (pn > MAXNORM) sc *= MAXNORM / pn;
    HBOUT[blockIdx.x * D + lane] = v0 * sc;
    HBOUT[blockIdx.x * D + lane + 64] = v1 * sc;
}

// ---------------- W split: W -> bf16 hi + lo (row-major, same layout) --------

__global__ __launch_bounds__(256) void prepW(const float* __restrict__ W1,
                                             const float* __restrict__ W2,
                                             uint16_t* __restrict__ Whi1,
                                             uint16_t* __restrict__ Wlo1,
                                             uint16_t* __restrict__ Whi2,
                                             uint16_t* __restrict__ Wlo2) {
    int i = blockIdx.x * 256 + threadIdx.x;  // 0..16383
    float a1 = W1[i];
    uint16_t h1 = f2bf(a1);
    Whi1[i] = h1;
    Wlo1[i] = f2bf(a1 - bf2f(h1));
    float a2 = W2[i];
    uint16_t h2 = f2bf(a2);
    Whi2[i] = h2;
    Wlo2[i] = f2bf(a2 - bf2f(h2));
}

// ---------------- raw row norms of X (for layer-1 encoder fold) --------------

__global__ __launch_bounds__(256) void rowNorms(const float* __restrict__ X,
                                                float* __restrict__ XN, int n) {
    int lane = threadIdx.x & 63;
    int wv = (blockIdx.x * 256 + threadIdx.x) >> 6;
    int nw = (gridDim.x * 256) >> 6;
    for (int r = wv; r < n; r += nw) {
        float2 v = *(const float2*)(X + (size_t)r * D + lane * 2);
        float nn = sqrtf(waveAllReduce(v.x * v.x + v.y * v.y));
        if (lane == 0) XN[r] = nn;
    }
}

// ---------------- bucket binning ---------------------------------------------

__global__ __launch_bounds__(256) void bucketHisto(const int* __restrict__ DST,
                                                   int* __restrict__ bcnt, int E, int B) {
    __shared__ int cnt[1024];
    int tid = threadIdx.x;
    for (int i = tid; i < B; i += 256) cnt[i] = 0;
    __syncthreads();
    int start = blockIdx.x * 8192;
    int endE = min(start + 8192, E);
    for (int e = start + tid; e < endE; e += 256)
        atomicAdd(&cnt[DST[e] >> BKT_BITS], 1);
    __syncthreads();
    for (int i = tid; i < B; i += 256)
        if (cnt[i]) atomicAdd(&bcnt[i], cnt[i]);
}

// single block: exclusive scan of bcnt (B <= 1024) -> boff, gcur; rp[n]=boff[B]=E
__global__ __launch_bounds__(1024) void bucketScan(const int* __restrict__ bcnt,
                                                   int* __restrict__ boff,
                                                   int* __restrict__ gcur,
                                                   int* __restrict__ rp_last,
                                                   int B, int E) {
    __shared__ int sd[1024];
    int tid = threadIdx.x;
    int v = (tid < B) ? bcnt[tid] : 0;
    sd[tid] = v;
    __syncthreads();
    for (int off = 1; off < 1024; off <<= 1) {
        int t = (tid >= off) ? sd[tid - off] : 0;
        __syncthreads();
        sd[tid] += t;
        __syncthreads();
    }
    int ex = sd[tid] - v;
    if (tid < B) { boff[tid] = ex; gcur[tid] = ex; }
    if (tid == 0) { boff[B] = E; *rp_last = E; }
}

__global__ __launch_bounds__(256) void binEdges(const int* __restrict__ DST,
                                                const int* __restrict__ SRC,
                                                const float* __restrict__ EW,
                                                int* __restrict__ gcur,
                                                int2* __restrict__ binned, int E, int B) {
    __shared__ int cnt[1024];
    __shared__ int base[1024];
    int tid = threadIdx.x;
    int start = blockIdx.x * 8192;
    int endE = min(start + 8192, E);
    for (int i = tid; i < B; i += 256) cnt[i] = 0;
    __syncthreads();
    for (int e = start + tid; e < endE; e += 256)
        atomicAdd(&cnt[DST[e] >> BKT_BITS], 1);
    __syncthreads();
    for (int i = tid; i < B; i += 256) {
        int c = cnt[i];
        base[i] = (c > 0) ? atomicAdd(&gcur[i], c) : 0;
        cnt[i] = 0;
    }
    __syncthreads();
    for (int e = start + tid; e < endE; e += 256) {
        int d = DST[e];
        int bk = d >> BKT_BITS;
        int r = atomicAdd(&cnt[bk], 1);
        binned[base[bk] + r] =
            make_int2(SRC[e] | ((d & (BKT_NODES - 1)) << 24), __float_as_int(EW[e]));
    }
}

// ---------------- per-bucket counting sort -> exact CSR ----------------------

__global__ __launch_bounds__(256) void perBucketSort(int2* __restrict__ binned,
                                                     const int* __restrict__ boff,
                                                     int* __restrict__ rp, int n) {
    __shared__ int cnt[BKT_NODES];
    __shared__ int cur[BKT_NODES];
    __shared__ int2 buf[BKT_CAP];
    int tid = threadIdx.x;
    int b = blockIdx.x;
    int beg = boff[b], end = boff[b + 1];

    if (tid < BKT_NODES) cnt[tid] = 0;
    __syncthreads();
    for (int e = beg + tid; e < end; e += 256)
        atomicAdd(&cnt[((uint32_t)binned[e].x) >> 24], 1);
    __syncthreads();
    // exclusive scan over 128 counters (Hillis-Steele, uniform syncs)
    int v = (tid < BKT_NODES) ? cnt[tid] : 0;
    if (tid < BKT_NODES) cur[tid] = v;
    __syncthreads();
    for (int off = 1; off < BKT_NODES; off <<= 1) {
        int t = (tid < BKT_NODES && tid >= off) ? cur[tid - off] : 0;
        __syncthreads();
        if (tid < BKT_NODES) cur[tid] += t;
        __syncthreads();
    }
    if (tid < BKT_NODES) {
        int ex = cur[tid] - v;
        int g = b * BKT_NODES + tid;
        if (g < n) rp[g] = beg + ex;
        cur[tid] = ex;   // scatter cursor
    }
    __syncthreads();
    for (int e = beg + tid; e < end; e += 256) {
        int2 pr = binned[e];
        int dl = ((uint32_t)pr.x) >> 24;
        int pos = atomicAdd(&cur[dl], 1);
        if (pos < BKT_CAP) buf[pos] = make_int2(pr.x & 0x00FFFFFF, pr.y);
    }
    __syncthreads();
    int cnt_tot = end - beg;
    for (int i = tid; i < cnt_tot && i < BKT_CAP; i += 256)
        binned[beg + i] = buf[i];
}

// ---------------- MFMA GEMM (bf16x3 split) + HypLinear epilogue --------------
// No LDS, no barriers. Wave owns 16 rows x 128 cols.
// mx = p @ W^T via D = A*B: A[m][k] = p[row][k] (m = lane&15, k-chunk = lane>>4),
// B[k][n] = W[j][k] (n = j = lane&15) -- W row-major IS the B layout; no transpose.
// fp32 emulated as hi*hi + hi*lo + lo*hi (bf16 split, ~2^-17 rel err).
// C/D: col = lane&15, row = 4*(lane>>4) + reg  [HW-verified mapping].

__device__ __forceinline__ void split8(const float* v, short8* hi, short8* lo) {
    union { uint32_t u[4]; short8 s; } H, L;
#pragma unroll
    for (int i = 0; i < 4; i++) {
        uint16_t h0 = f2bf(v[2 * i]), h1 = f2bf(v[2 * i + 1]);
        uint16_t l0 = f2bf(v[2 * i] - bf2f(h0));
        uint16_t l1 = f2bf(v[2 * i + 1] - bf2f(h1));
        H.u[i] = (uint32_t)h0 | ((uint32_t)h1 << 16);
        L.u[i] = (uint32_t)l0 | ((uint32_t)l1 << 16);
    }
    *hi = H.s;
    *lo = L.s;
}

template <bool ENCODE>
__global__ __launch_bounds__(256) void gemmM(const float* __restrict__ A,
                                             const uint16_t* __restrict__ Whi,
                                             const uint16_t* __restrict__ Wlo,
                                             const float* __restrict__ XN,
                                             const float* __restrict__ HB,
                                             uint16_t* __restrict__ XT, int n) {
    int tid = threadIdx.x;
    int lane = tid & 63;
    int wv = tid >> 6;
    int tx = lane & 15;     // A row / B col / C col index within tile
    int q = lane >> 4;      // k-group (0..3)
    int rowBase = blockIdx.x * 64 + wv * 16;

    // hb fragment for epilogue (col j = 16c + tx)
    float hbf[8];
#pragma unroll
    for (int c = 0; c < 8; c++) hbf[c] = HB[16 * c + tx];
    float hbsq = 0.f;
#pragma unroll
    for (int c = 0; c < 8; c++) hbsq += hbf[c] * hbf[c];
    float hb2 = reduce16(hbsq);

    // ---- A fragments: row = rowBase + tx, k = 32t + 8q + i ----
    int gr = rowBase + tx;
    if (gr >= n) gr = n - 1;  // clamp; epilogue guarded
    short8 ahi[4], alo[4];
#pragma unroll
    for (int t = 0; t < 4; t++) {
        const float4* ap = (const float4*)(A + (size_t)gr * D + t * 32 + q * 8);
        float4 v0 = ap[0], v1 = ap[1];
        float v[8] = {v0.x, v0.y, v0.z, v0.w, v1.x, v1.y, v1.z, v1.w};
        split8(v, &ahi[t], &alo[t]);
    }

    // ---- MFMA: 8 col-tiles x 4 k-steps x 3 products ----
    float4v acc[8];
#pragma unroll
    for (int c = 0; c < 8; c++) acc[c] = (float4v){0.f, 0.f, 0.f, 0.f};
#pragma unroll
    for (int ct = 0; ct < 8; ct++) {
        const uint16_t* wh = Whi + (size_t)(16 * ct + tx) * D + q * 8;
        const uint16_t* wl = Wlo + (size_t)(16 * ct + tx) * D + q * 8;
#pragma unroll
        for (int t = 0; t < 4; t++) {
            short8 bh = *(const short8*)(wh + t * 32);
            short8 bl = *(const short8*)(wl + t * 32);
            acc[ct] = __builtin_amdgcn_mfma_f32_16x16x32_bf16(ahi[t], bh, acc[ct], 0, 0, 0);
            acc[ct] = __builtin_amdgcn_mfma_f32_16x16x32_bf16(ahi[t], bl, acc[ct], 0, 0, 0);
            acc[ct] = __builtin_amdgcn_mfma_f32_16x16x32_bf16(alo[t], bh, acc[ct], 0, 0, 0);
        }
    }

    // ---- fused epilogue: row = rowBase + 4q + p; cols 16c + tx --------------
#pragma unroll
    for (int p = 0; p < 4; p++) {
        int row = rowBase + 4 * q + p;
        if (row >= n) continue;   // uniform within the 16-lane group
        float s = 0.f;
#pragma unroll
        for (int c = 0; c < 8; c++) s += acc[c][p] * acc[c][p];
        float yn2 = reduce16(s);
        float sc, xns;
        if (ENCODE) {
            float nn = fmaxf(XN[row], 1e-15f);
            float t = tanhf(nn);
            sc = t / nn;                        // expmap0 scale
            float pn = fmaxf(t, 1e-15f);
            if (pn > MAXNORM) { sc *= MAXNORM / pn; pn = MAXNORM; }  // proj
            xns = pn;
        } else {
            sc = 1.0f;
            xns = fmaxf(XN[row], 1e-15f);
        }
        float mxn2 = sc * sc * yn2;
        float mxn = fmaxf(sqrtf(mxn2), 1e-15f);
        float arg = (mxn / xns) * atanhf(fminf(xns, ART_CLAMP));
        float t = tanhf(arg);
        float s2 = (mxn2 == 0.0f) ? 0.0f : (sc * t / mxn);  // zero-row guard
        float h[8];
#pragma unroll
        for (int c = 0; c < 8; c++) h[c] = acc[c][p] * s2;
        float rn = fmaxf(t, 1e-15f);   // ||res|| == t analytically
        float hn = rn;
        if (rn > MAXNORM) {
            float f = MAXNORM / rn;
#pragma unroll
            for (int c = 0; c < 8; c++) h[c] *= f;
            hn = MAXNORM;
        }
        float x2 = hn * hn;
        float d0 = 0.f;
#pragma unroll
        for (int c = 0; c < 8; c++) d0 += h[c] * hbf[c];
        float xy = reduce16(d0);
        float k1 = 1.0f + 2.0f * xy + hb2;
        float k2 = 1.0f - x2;
        float den = fmaxf(1.0f + 2.0f * xy + x2 * hb2, 1e-15f);
        float av[8];
        float s3 = 0.f;
#pragma unroll
        for (int c = 0; c < 8; c++) {
            av[c] = (k1 * h[c] + k2 * hbf[c]) / den;
            s3 += av[c] * av[c];
        }
        float an = fmaxf(sqrtf(reduce16(s3)), 1e-15f);
        float fproj = 1.0f;
        if (an > MAXNORM) { fproj = MAXNORM / an; an = MAXNORM; }
        float lm = fproj * atanhf(fminf(an, ART_CLAMP)) / an;  // proj+logmap0
        uint16_t* o = XT + (size_t)row * D + tx;
#pragma unroll
        for (int c = 0; c < 8; c++) o[16 * c] = f2bf(av[c] * lm);
    }
}

// ---------------- CSR aggregation + HypAct -----------------------------------
// Wave per node (max MLP for the random gather): bf16 rows, fp32 accumulate,
// stage-C epilogue inline. STORE_HN: store analytic output norm.

template <bool STORE_HN>
__global__ __launch_bounds__(256) void aggC(const uint16_t* __restrict__ XT,
                                            const int* __restrict__ rp,
                                            const int2* __restrict__ sorted,
                                            float* __restrict__ OUT,
                                            float* __restrict__ HN, int n) {
    int g = (blockIdx.x * 256 + threadIdx.x) >> 6;
    int lane = threadIdx.x & 63;
    if (g >= n) return;
    int beg = rp[g], end = rp[g + 1];
    float a0 = 0.f, a1 = 0.f;
    int j = beg;
    for (; j + 3 < end; j += 4) {
        int2 s0 = sorted[j], s1 = sorted[j + 1], s2 = sorted[j + 2], s3 = sorted[j + 3];
        uint32_t u0 = ((const uint32_t*)(XT + (size_t)s0.x * D))[lane];
        uint32_t u1 = ((const uint32_t*)(XT + (size_t)s1.x * D))[lane];
        uint32_t u2 = ((const uint32_t*)(XT + (size_t)s2.x * D))[lane];
        uint32_t u3 = ((const uint32_t*)(XT + (size_t)s3.x * D))[lane];
        float w0 = __int_as_float(s0.y), w1 = __int_as_float(s1.y);
        float w2 = __int_as_float(s2.y), w3 = __int_as_float(s3.y);
        a0 += __uint_as_float(u0 << 16) * w0 + __uint_as_float(u1 << 16) * w1 +
              __uint_as_float(u2 << 16) * w2 + __uint_as_float(u3 << 16) * w3;
        a1 += __uint_as_float(u0 & 0xFFFF0000u) * w0 + __uint_as_float(u1 & 0xFFFF0000u) * w1 +
              __uint_as_float(u2 & 0xFFFF0000u) * w2 + __uint_as_float(u3 & 0xFFFF0000u) * w3;
    }
    for (; j < end; j++) {
        int2 s0 = sorted[j];
        uint32_t u0 = ((const uint32_t*)(XT + (size_t)s0.x * D))[lane];
        float w0 = __int_as_float(s0.y);
        a0 += __uint_as_float(u0 << 16) * w0;
        a1 += __uint_as_float(u0 & 0xFFFF0000u) * w0;
    }
    // ---- stage C inline ----
    float nn = fmaxf(sqrtf(waveAllReduce(a0 * a0 + a1 * a1)), 1e-15f);
    float t = tanhf(nn);
    float sc = t / nn;                       // expmap0
    float pn = fmaxf(t, 1e-15f);
    if (pn > MAXNORM) { sc *= MAXNORM / pn; pn = MAXNORM; }  // proj
    float lm = atanhf(fminf(pn, ART_CLAMP)) / pn;            // logmap0
    float r0 = fmaxf(lm * sc * a0, 0.f);     // relu in tangent space
    float r1 = fmaxf(lm * sc * a1, 0.f);
    float rn = fmaxf(sqrtf(waveAllReduce(r0 * r0 + r1 * r1)), 1e-15f);
    float t2 = tanhf(rn);
    float sc2 = t2 / rn;                     // expmap0 at c_out
    float on = fmaxf(t2, 1e-15f);
    if (on > MAXNORM) { sc2 *= MAXNORM / on; on = MAXNORM; }
    *(float2*)(OUT + (size_t)g * D + lane * 2) = make_float2(r0 * sc2, r1 * sc2);
    if (STORE_HN && lane == 0) HN[g] = on;   // next layer's _norm(x)
}

// ---------------- launcher ---------------------------------------------------

extern "C" void kernel_launch(void* const* d_in, const int* in_sizes, int n_in,
                              void* d_out, int out_size, void* d_ws, size_t ws_size,
                              hipStream_t stream) {
    const float* x  = (const float*)d_in[0];
    const int*   ei = (const int*)d_in[1];
    const float* ew = (const float*)d_in[2];
    const float* w1 = (const float*)d_in[3];
    const float* b1 = (const float*)d_in[4];
    const float* w2 = (const float*)d_in[5];
    const float* b2 = (const float*)d_in[6];
    int n = in_sizes[0] / D;
    int E = in_sizes[2];
    int B = (n + BKT_NODES - 1) >> BKT_BITS;    // 782 for n=100000 (<= 1024)

    // workspace layout (~40 MB)
    uint16_t* xtb = (uint16_t*)d_ws;               // n*D bf16
    int*   bcnt = (int*)(xtb + (size_t)n * D);     // 1024
    int*   boff = bcnt + 1024;                     // 1025
    int*   gcur = boff + 1025;                     // 1024
    int*   rp   = gcur + 1024;                     // n+1
    float* xn   = (float*)(rp + n + 1);            // n (X norms, then H norms)
    uint16_t* whi1 = (uint16_t*)(xn + n);          // 128*128 bf16
    uint16_t* wlo1 = whi1 + 128 * 128;
    uint16_t* whi2 = wlo1 + 128 * 128;
    uint16_t* wlo2 = whi2 + 128 * 128;
    float* hb = (float*)(wlo2 + 128 * 128);        // 2*D
    uintptr_t p = (uintptr_t)(hb + 2 * D);
    int2* binned = (int2*)((p + 15) & ~(uintptr_t)15);  // E pairs (binned, then CSR-sorted)
    float* Hd = (float*)d_out;                     // H1 scratch + final out

    const int* dst = ei;      // edge_index[0] = segment ids (destinations)
    const int* src = ei + E;  // edge_index[1] = gather sources

    const int gE8 = (E + 8191) / 8192;
    const int gG = (n + 63) / 64;      // gemm blocks (64 rows each)
    const int gAgg = (n + 3) / 4;      // wave per node

    biasKernel<<<2, 64, 0, stream>>>(b1, b2, hb);
    prepW<<<64, 256, 0, stream>>>(w1, w2, whi1, wlo1, whi2, wlo2);
    rowNorms<<<1024, 256, 0, stream>>>(x, xn, n);

    // ---- CSR build: bucket-bin then per-bucket LDS counting sort ----
    hipMemsetAsync(bcnt, 0, 1024 * sizeof(int), stream);
    bucketHisto<<<gE8, 256, 0, stream>>>(dst, bcnt, E, B);
    bucketScan<<<1, 1024, 0, stream>>>(bcnt, boff, gcur, rp + n, B, E);
    binEdges<<<gE8, 256, 0, stream>>>(dst, src, ew, gcur, binned, E, B);
    perBucketSort<<<B, 256, 0, stream>>>(binned, boff, rp, n);

    // ---- layer 1 (encoder folded into gemmM epilogue) ----
    gemmM<true><<<gG, 256, 0, stream>>>(x, whi1, wlo1, xn, hb, xtb, n);      // -> bf16 T1
    aggC<true><<<gAgg, 256, 0, stream>>>(xtb, rp, binned, Hd, xn, n);        // -> H1 + hn

    // ---- layer 2 ----
    gemmM<false><<<gG, 256, 0, stream>>>(Hd, whi2, wlo2, xn, hb + D, xtb, n); // -> bf16 T2
    aggC<false><<<gAgg, 256, 0, stream>>>(xtb, rp, binned, (float*)d_out, nullptr, n);
}